// Round 1
// baseline (8120.718 us; speedup 1.0000x reference)
//
#include <hip/hip_runtime.h>
#include <math.h>

// Problem constants (B,S,D fixed by reference setup_inputs)
#define B 64
#define S 2048
#define D 64
// TEMPERATURE = 8.0 -> multiply scores by 1/8
#define INV_TEMP 0.125f

// ---------------------------------------------------------------------------
// Fused kernel: per block = 64 q-rows, 256 threads, one pass over K/V tiles.
//   thread (tr = t>>4 in 0..15, tc = t&15): owns rows tr*4..+3, cols tc*4..+3
//   For each 64-wide k-tile:
//     scores 4x4 = QK^T (register tiled, LDS broadcast reads)
//     e = mask ? 0 : exp(s/8)  -> written UNNORMALIZED to attn global,
//                                 stashed in LDS for the PV step
//     acc 4x4 += e-tile @ V-tile
//   End: out = acc * (1/rowsum) (rowsum reduced via shfl over the 16 tc lanes)
//   attn is renormalized by a second, pure-BW kernel.
// LDS tiles are 64x64 with XOR-swizzled columns (col ^= ((row>>2)&7)<<2) so
// the 16-distinct-row b128 reads are bank-conflict-free. Total LDS = 64 KiB
// -> 2 blocks/CU.
// ---------------------------------------------------------------------------
__global__ __launch_bounds__(256) void attn_fused_kernel(
    const float* __restrict__ qp, const float* __restrict__ kp,
    const float* __restrict__ vp, const int* __restrict__ maskp,
    float* __restrict__ attnp, float* __restrict__ outp)
{
    __shared__ float qs[64][64];   // swizzled
    __shared__ float ks[64][64];   // swizzled
    __shared__ float vs[64][64];   // linear (reads are row-uniform, free)
    __shared__ float es[64][64];   // swizzled

    // XCD-chunked block swizzle: 2048 blocks, 8 XCDs -> 256 contiguous each,
    // so same-batch blocks share an XCD's L2 for K/V.
    const int bid = blockIdx.x;
    const int swz = (bid & 7) * 256 + (bid >> 3);
    const int b   = swz >> 5;          // 64 batches
    const int r0  = (swz & 31) * 64;   // 32 row-tiles per batch

    const int t    = threadIdx.x;
    const int tr   = t >> 4;           // 0..15 row group
    const int tc   = t & 15;           // 0..15 col group
    const int rr   = tr * 4;           // local row base
    const int cc   = tc * 4;           // local col/d base
    const int qxor = (tr & 7) << 2;    // read swizzle for qs rows rr..rr+3
    const int kxor = (tc & 7) << 2;    // read swizzle for ks rows cc..cc+3

    const float* kbase = kp + (size_t)b * S * D;
    const float* vbase = vp + (size_t)b * S * D;

    // ---- stage Q tile [64][64] (once per block), swizzled ----
    {
        const float4* qsrc = (const float4*)(qp + ((size_t)b * S + r0) * D);
#pragma unroll
        for (int i = 0; i < 4; ++i) {
            int idx = t + 256 * i;          // float4 index 0..1023
            int r = idx >> 4;               // 16 float4 per row
            int c = (idx & 15) * 4;
            *(float4*)&qs[r][c ^ (((r >> 2) & 7) << 2)] = qsrc[idx];
        }
    }

    float4 acc[4];
#pragma unroll
    for (int i = 0; i < 4; ++i) acc[i] = make_float4(0.f, 0.f, 0.f, 0.f);
    float rs[4] = {0.f, 0.f, 0.f, 0.f};

    // ---- prologue: stage K/V tile 0 ----
    float4 kreg[4], vreg[4];
    {
        const float4* ksrc = (const float4*)kbase;
        const float4* vsrc = (const float4*)vbase;
#pragma unroll
        for (int i = 0; i < 4; ++i) {
            kreg[i] = ksrc[t + 256 * i];
            vreg[i] = vsrc[t + 256 * i];
        }
    }
#pragma unroll
    for (int i = 0; i < 4; ++i) {
        int idx = t + 256 * i;
        int r = idx >> 4;
        int c = (idx & 15) * 4;
        *(float4*)&ks[r][c ^ (((r >> 2) & 7) << 2)] = kreg[i];
        *(float4*)&vs[r][c] = vreg[i];
    }
    __syncthreads();   // B1: tile 0 (and Q) visible

#pragma unroll 1
    for (int kt = 0; kt < 32; ++kt) {
        // Issue next tile's global loads early (consumed after B3) so HBM
        // latency hides under this tile's compute.
        if (kt < 31) {
            const float4* ksrc = (const float4*)(kbase + (size_t)(kt + 1) * 64 * D);
            const float4* vsrc = (const float4*)(vbase + (size_t)(kt + 1) * 64 * D);
#pragma unroll
            for (int i = 0; i < 4; ++i) {
                kreg[i] = ksrc[t + 256 * i];
                vreg[i] = vsrc[t + 256 * i];
            }
        }
        // Mask for this tile (independent of scores -> issued early too)
        int4 m4[4];
#pragma unroll
        for (int i = 0; i < 4; ++i) {
            m4[i] = *(const int4*)(maskp + ((size_t)b * S + r0 + rr + i) * S
                                   + (size_t)kt * 64 + cc);
        }

        // ---- scores: 4x4 register tile of QK^T ----
        float sc[4][4];
#pragma unroll
        for (int i = 0; i < 4; ++i)
#pragma unroll
            for (int j = 0; j < 4; ++j) sc[i][j] = 0.f;

#pragma unroll
        for (int dstep = 0; dstep < 16; ++dstep) {
            const int dc = dstep * 4;
            float4 q4[4], k4[4];
#pragma unroll
            for (int i = 0; i < 4; ++i) q4[i] = *(const float4*)&qs[rr + i][dc ^ qxor];
#pragma unroll
            for (int j = 0; j < 4; ++j) k4[j] = *(const float4*)&ks[cc + j][dc ^ kxor];
#pragma unroll
            for (int i = 0; i < 4; ++i)
#pragma unroll
                for (int j = 0; j < 4; ++j)
                    sc[i][j] += q4[i].x * k4[j].x + q4[i].y * k4[j].y
                              + q4[i].z * k4[j].z + q4[i].w * k4[j].w;
        }

        // ---- mask + exp; write unnormalized e to global attn + LDS ----
        const size_t abase = ((size_t)b * S + r0 + rr) * S + (size_t)kt * 64 + cc;
#pragma unroll
        for (int i = 0; i < 4; ++i) {
            float4 e4;
            e4.x = m4[i].x ? 0.f : __expf(sc[i][0] * INV_TEMP);
            e4.y = m4[i].y ? 0.f : __expf(sc[i][1] * INV_TEMP);
            e4.z = m4[i].z ? 0.f : __expf(sc[i][2] * INV_TEMP);
            e4.w = m4[i].w ? 0.f : __expf(sc[i][3] * INV_TEMP);
            rs[i] += (e4.x + e4.y) + (e4.z + e4.w);
            *(float4*)&es[rr + i][cc ^ qxor] = e4;
            *(float4*)(attnp + abase + (size_t)i * S) = e4;
        }
        __syncthreads();   // B2: es complete (scores phase done in all waves)

        // ---- PV: acc[4][4] += E-tile @ V-tile ----
#pragma unroll
        for (int kk = 0; kk < 64; kk += 4) {
            float4 e4[4], v4[4];
#pragma unroll
            for (int i = 0; i < 4; ++i) e4[i] = *(const float4*)&es[rr + i][kk ^ qxor];
#pragma unroll
            for (int u = 0; u < 4; ++u) v4[u] = *(const float4*)&vs[kk + u][cc];
#pragma unroll
            for (int i = 0; i < 4; ++i) {
                acc[i].x += e4[i].x * v4[0].x + e4[i].y * v4[1].x
                          + e4[i].z * v4[2].x + e4[i].w * v4[3].x;
                acc[i].y += e4[i].x * v4[0].y + e4[i].y * v4[1].y
                          + e4[i].z * v4[2].y + e4[i].w * v4[3].y;
                acc[i].z += e4[i].x * v4[0].z + e4[i].y * v4[1].z
                          + e4[i].z * v4[2].z + e4[i].w * v4[3].z;
                acc[i].w += e4[i].x * v4[0].w + e4[i].y * v4[1].w
                          + e4[i].z * v4[2].w + e4[i].w * v4[3].w;
            }
        }
        __syncthreads();   // B3: ks/vs/es consumed

        if (kt < 31) {
#pragma unroll
            for (int i = 0; i < 4; ++i) {
                int idx = t + 256 * i;
                int r = idx >> 4;
                int c = (idx & 15) * 4;
                *(float4*)&ks[r][c ^ (((r >> 2) & 7) << 2)] = kreg[i];
                *(float4*)&vs[r][c] = vreg[i];
            }
            __syncthreads();   // B1: next tile visible
        }
    }

    // ---- epilogue: reduce rowsums over the 16 tc lanes, write out*inv ----
#pragma unroll
    for (int i = 0; i < 4; ++i) {
        float s = rs[i];
        s += __shfl_xor(s, 1, 64);
        s += __shfl_xor(s, 2, 64);
        s += __shfl_xor(s, 4, 64);
        s += __shfl_xor(s, 8, 64);
        const float inv = 1.f / s;
        float4 o;
        o.x = acc[i].x * inv;
        o.y = acc[i].y * inv;
        o.z = acc[i].z * inv;
        o.w = acc[i].w * inv;
        *(float4*)(outp + ((size_t)b * S + r0 + rr + i) * D + cc) = o;
    }
}

// ---------------------------------------------------------------------------
// Renormalize attn in place: one wave per row, pure HBM streaming.
// grid (S/4, B), block 256 = 4 waves.
// ---------------------------------------------------------------------------
__global__ __launch_bounds__(256) void attn_norm_kernel(float* __restrict__ attnp)
{
    const int b    = blockIdx.y;
    const int wave = threadIdx.x >> 6;
    const int lane = threadIdx.x & 63;
    const int row  = blockIdx.x * 4 + wave;

    float4* arow = (float4*)(attnp + ((size_t)b * S + row) * S);

    float4 x[8];
    float s = 0.f;
#pragma unroll
    for (int i = 0; i < 8; ++i) {
        x[i] = arow[lane + 64 * i];
        s += (x[i].x + x[i].y) + (x[i].z + x[i].w);
    }
#pragma unroll
    for (int off = 32; off > 0; off >>= 1) s += __shfl_xor(s, off, 64);
    const float inv = 1.f / s;
#pragma unroll
    for (int i = 0; i < 8; ++i) {
        float4 y;
        y.x = x[i].x * inv;
        y.y = x[i].y * inv;
        y.z = x[i].z * inv;
        y.w = x[i].w * inv;
        arow[lane + 64 * i] = y;
    }
}

// ---------------------------------------------------------------------------
extern "C" void kernel_launch(void* const* d_in, const int* in_sizes, int n_in,
                              void* d_out, int out_size, void* d_ws, size_t ws_size,
                              hipStream_t stream) {
    const float* q = (const float*)d_in[0];
    const float* k = (const float*)d_in[1];
    const float* v = (const float*)d_in[2];
    const int* mask = (const int*)d_in[3];   // bool -> int32 in harness

    float* out  = (float*)d_out;                       // (B,S,D) first
    float* attn = out + (size_t)B * S * D;             // then (B,S,S)

    attn_fused_kernel<<<dim3((S / 64) * B), 256, 0, stream>>>(q, k, v, mask, attn, out);
    attn_norm_kernel<<<dim3(S / 4, B), 256, 0, stream>>>(attn);
}